// Round 1
// baseline (492.708 us; speedup 1.0000x reference)
//
#include <hip/hip_runtime.h>
#include <hip/hip_bf16.h>

// Problem constants
#define NB    8
#define SQN   2048
#define SKN   4096
#define DDIM  512
#define DVDIM 256
#define NROWS (NB*SQN)      // 16384
#define SPLIT 2
#define SKH   (SKN/SPLIT)   // 2048 keys per split

typedef __attribute__((ext_vector_type(8))) short bf16x8;   // 8 bf16 = 4 VGPRs (MFMA A/B frag)
typedef __attribute__((ext_vector_type(4))) short bf16x4;
typedef __attribute__((ext_vector_type(4))) float f32x4;    // MFMA C/D frag

// fp32 -> bf16 round-to-nearest-even, bit pattern as short
__device__ __forceinline__ short f2bf(float f) {
    unsigned u = __float_as_uint(f);
    return (short)((u + 0x7FFFu + ((u >> 16) & 1u)) >> 16);
}

// async global->LDS, 16B per lane; LDS dst = wave-uniform base + lane*16
__device__ __forceinline__ void gload_lds16(const void* g, void* l) {
    __builtin_amdgcn_global_load_lds(
        (const __attribute__((address_space(1))) unsigned int*)g,
        (__attribute__((address_space(3))) unsigned int*)l, 16, 0, 0);
}

// ---------------------------------------------------------------------------
// Generic NT GEMM: C[m][n] = sum_k A[m][k]*B[n][k], A:MxK f32, B:NxK f32,
// C:MxN bf16 row-major. Tiles 64x64, block=256 (4 waves x 16 rows), Kc=128.
// fp32->bf16 conversion fused into LDS staging.
// grid = (M/64, N/64)
// ---------------------------------------------------------------------------
__global__ __launch_bounds__(256, 2) void gemm_nt_f32_bf16(
    const float* __restrict__ A, const float* __restrict__ Bm,
    unsigned short* __restrict__ C, int M, int N, int K)
{
    __shared__ short sA[64*128];   // 16 KB
    __shared__ short sB[64*128];   // 16 KB
    const int tid  = threadIdx.x;
    const int wave = tid >> 6;
    const int lane = tid & 63;
    const int quad = lane >> 4;
    const int l15  = lane & 15;
    const int m0 = blockIdx.x * 64;
    const int n0 = blockIdx.y * 64;

    f32x4 acc[4];
    #pragma unroll
    for (int n = 0; n < 4; ++n) { acc[n][0]=0.f; acc[n][1]=0.f; acc[n][2]=0.f; acc[n][3]=0.f; }

    for (int kc = 0; kc < K; kc += 128) {
        __syncthreads();
        // stage A and B tiles (64x128 each), convert fp32->bf16 in regs
        #pragma unroll
        for (int it = 0; it < 8; ++it) {
            int f = it*1024 + tid*4;          // element index in 64x128 tile
            int row = f >> 7, col = f & 127;
            float4 av = *(const float4*)(A + (size_t)(m0+row)*K + kc + col);
            bf16x4 a4; a4[0]=f2bf(av.x); a4[1]=f2bf(av.y); a4[2]=f2bf(av.z); a4[3]=f2bf(av.w);
            *(bf16x4*)(sA + f) = a4;
            float4 bv = *(const float4*)(Bm + (size_t)(n0+row)*K + kc + col);
            bf16x4 b4; b4[0]=f2bf(bv.x); b4[1]=f2bf(bv.y); b4[2]=f2bf(bv.z); b4[3]=f2bf(bv.w);
            *(bf16x4*)(sB + f) = b4;
        }
        __syncthreads();
        #pragma unroll
        for (int t = 0; t < 4; ++t) {
            bf16x8 af = *(const bf16x8*)(sA + (wave*16 + l15)*128 + t*32 + quad*8);
            #pragma unroll
            for (int n = 0; n < 4; ++n) {
                bf16x8 bfr = *(const bf16x8*)(sB + (n*16 + l15)*128 + t*32 + quad*8);
                acc[n] = __builtin_amdgcn_mfma_f32_16x16x32_bf16(af, bfr, acc[n], 0, 0, 0);
            }
        }
    }
    // epilogue: D row=quad*4+r (within wave's 16 rows), col=l15 (within n-subtile)
    #pragma unroll
    for (int n = 0; n < 4; ++n)
        #pragma unroll
        for (int r = 0; r < 4; ++r) {
            int m  = m0 + wave*16 + quad*4 + r;
            int nn = n0 + n*16 + l15;
            C[(size_t)m*N + nn] = (unsigned short)f2bf(acc[n][r]);
        }
}

// ---------------------------------------------------------------------------
// Fused attention (one SK split half per block):
//  grid = (NROWS/64, SPLIT), block = 256 (4 waves x 16 Q-rows).
//  Q (x scale) held in registers as bf16 A-frags. K staged 64x128 chunks,
//  V^T staged 256x64, online softmax in C-layout, P->LDS->A-frag for PV.
//  Writes unnormalized O, m, l per split; combine kernel merges.
// ---------------------------------------------------------------------------
__global__ __launch_bounds__(256, 2) void attn_fused(
    const float* __restrict__ X,            // [16384][512] fp32
    const unsigned short* __restrict__ Kb,  // key bf16 [4096][512]
    const unsigned short* __restrict__ Vt,  // V^T bf16 [256][4096]
    float* __restrict__ Opart,              // [SPLIT][16384][256]
    float* __restrict__ Mpart,              // [SPLIT][16384]
    float* __restrict__ Lpart)              // [SPLIT][16384]
{
    __shared__ short sK[64*128];    // 16 KB, K chunk (64 keys x 128 d)
    __shared__ short sV[256*64];    // 32 KB, V^T tile (256 dv x 64 keys)
    __shared__ short sP[4*16*64];   // 8 KB, per-wave P buffer (wave-private)
    const int tid  = threadIdx.x;
    const int wave = tid >> 6;
    const int lane = tid & 63;
    const int quad = lane >> 4;
    const int l15  = lane & 15;
    const int q0   = blockIdx.x * 64;
    const int split = blockIdx.y;
    const float scale = 0.04419417382415922f;  // 1/sqrt(512)

    // Load Q fragments (scale folded in): A[m=l15][k=quad*8+j], 16 k-steps
    bf16x8 qf[16];
    {
        const float* xrow = X + (size_t)(q0 + wave*16 + l15) * DDIM;
        #pragma unroll
        for (int t = 0; t < 16; ++t) {
            float4 a = *(const float4*)(xrow + t*32 + quad*8);
            float4 b = *(const float4*)(xrow + t*32 + quad*8 + 4);
            bf16x8 q;
            q[0]=f2bf(a.x*scale); q[1]=f2bf(a.y*scale); q[2]=f2bf(a.z*scale); q[3]=f2bf(a.w*scale);
            q[4]=f2bf(b.x*scale); q[5]=f2bf(b.y*scale); q[6]=f2bf(b.z*scale); q[7]=f2bf(b.w*scale);
            qf[t] = q;
        }
    }

    f32x4 o[16];                    // O acc: 16 dv-subtiles x 4 rows (C-layout)
    #pragma unroll
    for (int i = 0; i < 16; ++i) { o[i][0]=0.f; o[i][1]=0.f; o[i][2]=0.f; o[i][3]=0.f; }
    float m_r[4] = {-1e30f,-1e30f,-1e30f,-1e30f};  // per-row running max (row=quad*4+r)
    float l_r[4] = {0.f,0.f,0.f,0.f};              // per-row running denom
    short* sPw = sP + wave*(16*64);

    for (int j = 0; j < SKH/64; ++j) {
        const int sk0 = split*SKH + j*64;
        f32x4 s[4];
        #pragma unroll
        for (int n = 0; n < 4; ++n) { s[n][0]=0.f; s[n][1]=0.f; s[n][2]=0.f; s[n][3]=0.f; }

        #pragma unroll
        for (int c = 0; c < 4; ++c) {
            __syncthreads();                       // LDS buffers free (prev chunk / prev tile PV done)
            if (c == 0) {
                // stage V^T tile: sV[dv][skl] <- Vt[dv][sk0+skl]
                #pragma unroll
                for (int it = 0; it < 8; ++it) {
                    int f = it*2048 + tid*8;
                    int dv = f >> 6, sc = f & 63;
                    gload_lds16(Vt + (size_t)dv*SKN + sk0 + sc,
                                (char*)sV + it*4096 + wave*1024);
                }
            }
            // stage K chunk: sK[row][col] <- Kb[sk0+row][c*128+col]
            #pragma unroll
            for (int it = 0; it < 4; ++it) {
                int f = it*2048 + tid*8;
                int row = f >> 7, col = f & 127;
                gload_lds16(Kb + (size_t)(sk0+row)*DDIM + c*128 + col,
                            (char*)sK + it*4096 + wave*1024);
            }
            __syncthreads();                       // staged data visible
            // S += Q_chunk * K_chunk^T
            #pragma unroll
            for (int t = 0; t < 4; ++t) {
                bf16x8 af = qf[c*4 + t];
                const int co = t*32 + quad*8;
                #pragma unroll
                for (int n = 0; n < 4; ++n) {
                    bf16x8 bfr = *(const bf16x8*)(sK + (n*16 + l15)*128 + co);
                    s[n] = __builtin_amdgcn_mfma_f32_16x16x32_bf16(af, bfr, s[n], 0, 0, 0);
                }
            }
        }

        // ---- online softmax (rows = quad*4+r; cols spread over 16-lane group) ----
        float alpha[4];
        float p[4][4];
        #pragma unroll
        for (int r = 0; r < 4; ++r) {
            float v = fmaxf(fmaxf(s[0][r], s[1][r]), fmaxf(s[2][r], s[3][r]));
            v = fmaxf(v, __shfl_xor(v, 1));
            v = fmaxf(v, __shfl_xor(v, 2));
            v = fmaxf(v, __shfl_xor(v, 4));
            v = fmaxf(v, __shfl_xor(v, 8));
            float mn = fmaxf(m_r[r], v);
            alpha[r] = __expf(m_r[r] - mn);
            m_r[r] = mn;
            float sum = 0.f;
            #pragma unroll
            for (int n = 0; n < 4; ++n) {
                float pv = __expf(s[n][r] - mn);
                p[n][r] = pv;
                sum += pv;
            }
            sum += __shfl_xor(sum, 1);
            sum += __shfl_xor(sum, 2);
            sum += __shfl_xor(sum, 4);
            sum += __shfl_xor(sum, 8);
            l_r[r] = l_r[r]*alpha[r] + sum;
        }
        // rescale O accumulator (alpha per row == per reg)
        #pragma unroll
        for (int n2 = 0; n2 < 16; ++n2)
            #pragma unroll
            for (int r = 0; r < 4; ++r) o[n2][r] *= alpha[r];
        // write P to wave-private LDS (C-layout scatter); same-wave read below,
        // so no barrier needed
        #pragma unroll
        for (int n = 0; n < 4; ++n)
            #pragma unroll
            for (int r = 0; r < 4; ++r)
                sPw[(quad*4 + r)*64 + n*16 + l15] = f2bf(p[n][r]);
        // ---- O += P * V^T : A=P[m=q][k=skl] from sPw, B=Vt[n=dv][k=skl] from sV
        #pragma unroll
        for (int t2 = 0; t2 < 2; ++t2) {
            bf16x8 af = *(const bf16x8*)(sPw + l15*64 + t2*32 + quad*8);
            #pragma unroll
            for (int n2 = 0; n2 < 16; ++n2) {
                bf16x8 bfr = *(const bf16x8*)(sV + (n2*16 + l15)*64 + t2*32 + quad*8);
                o[n2] = __builtin_amdgcn_mfma_f32_16x16x32_bf16(af, bfr, o[n2], 0, 0, 0);
            }
        }
    }

    // epilogue: unnormalized O + (m,l) per row
    const size_t base = (size_t)split * NROWS;
    #pragma unroll
    for (int r = 0; r < 4; ++r) {
        int row = q0 + wave*16 + quad*4 + r;
        if (l15 == 0) { Mpart[base + row] = m_r[r]; Lpart[base + row] = l_r[r]; }
        float* orow = Opart + (base + row) * (size_t)DVDIM;
        #pragma unroll
        for (int n2 = 0; n2 < 16; ++n2)
            orow[n2*16 + l15] = o[n2][r];
    }
}

// ---------------------------------------------------------------------------
// Combine the two SK-split partials: out = (O0*w0 + O1*w1)/(l0*w0 + l1*w1)
// grid = NROWS (one row per block), block = 256 (= DV)
// ---------------------------------------------------------------------------
__global__ void combine_splits(
    const float* __restrict__ Opart, const float* __restrict__ Mpart,
    const float* __restrict__ Lpart, float* __restrict__ out)
{
    const int row = blockIdx.x;
    const int dv  = threadIdx.x;
    const size_t idx = (size_t)row * DVDIM + dv;
    float m0 = Mpart[row],         m1 = Mpart[NROWS + row];
    float l0 = Lpart[row],         l1 = Lpart[NROWS + row];
    float M  = fmaxf(m0, m1);
    float w0 = __expf(m0 - M), w1 = __expf(m1 - M);
    float denom = l0*w0 + l1*w1;
    float o0 = Opart[idx];
    float o1 = Opart[(size_t)NROWS*DVDIM + idx];
    out[idx] = (o0*w0 + o1*w1) / denom;
}

extern "C" void kernel_launch(void* const* d_in, const int* in_sizes, int n_in,
                              void* d_out, int out_size, void* d_ws, size_t ws_size,
                              hipStream_t stream) {
    const float* X  = (const float*)d_in[0];   // [8,2048,512]
    const float* Y  = (const float*)d_in[1];   // [4096,512]
    const float* Z  = (const float*)d_in[2];   // [4096,512]
    const float* Wk = (const float*)d_in[3];   // [512,512]
    const float* Wv = (const float*)d_in[4];   // [256,512]
    // d_in[5] = rate (dropout is identity in eval)
    float* out = (float*)d_out;

    // workspace layout (~40.3 MB total)
    char* ws = (char*)d_ws;
    unsigned short* keyb = (unsigned short*)(ws);                  // 4 MB: key bf16 [4096][512]
    unsigned short* vtb  = (unsigned short*)(ws + (4u<<20));       // 2 MB: V^T bf16 [256][4096]
    float* Opart = (float*)(ws + (8u<<20));                        // 32 MB: [2][16384][256]
    float* Mpart = (float*)(ws + (8u<<20) + 33554432u);            // 128 KB
    float* Lpart = (float*)(ws + (8u<<20) + 33554432u + 131072u);  // 128 KB

    // key[s][d] = sum_c Y[s][c] * Wk[d][c]
    gemm_nt_f32_bf16<<<dim3(SKN/64, DDIM/64), dim3(256), 0, stream>>>(
        Y, Wk, keyb, SKN, DDIM, DDIM);
    // vt[d][s] = sum_c Wv[d][c] * Z[s][c]  (value transposed)
    gemm_nt_f32_bf16<<<dim3(DVDIM/64, SKN/64), dim3(256), 0, stream>>>(
        Wv, Z, vtb, DVDIM, SKN, DDIM);
    // fused attention over SK split halves
    attn_fused<<<dim3(NROWS/64, SPLIT), dim3(256), 0, stream>>>(
        X, keyb, vtb, Opart, Mpart, Lpart);
    // merge splits
    combine_splits<<<dim3(NROWS), dim3(256), 0, stream>>>(Opart, Mpart, Lpart, out);
}

// Round 2
// 311.741 us; speedup vs baseline: 1.5805x; 1.5805x over previous
//
#include <hip/hip_runtime.h>
#include <hip/hip_bf16.h>

// Problem constants
#define NB    8
#define SQN   2048
#define SKN   4096
#define DDIM  512
#define DVDIM 256
#define NROWS (NB*SQN)      // 16384
#define SPLIT 2
#define SKH   (SKN/SPLIT)   // 2048 keys per split

typedef __attribute__((ext_vector_type(8))) short bf16x8;   // 8 bf16 = 4 VGPRs (MFMA A/B frag)
typedef __attribute__((ext_vector_type(4))) short bf16x4;
typedef __attribute__((ext_vector_type(4))) float f32x4;    // MFMA C/D frag

// fp32 -> bf16 round-to-nearest-even, bit pattern as short
__device__ __forceinline__ short f2bf(float f) {
    unsigned u = __float_as_uint(f);
    return (short)((u + 0x7FFFu + ((u >> 16) & 1u)) >> 16);
}

// async global->LDS, 16B per lane; LDS dst = wave-uniform base + lane*16
__device__ __forceinline__ void gload_lds16(const void* g, void* l) {
    __builtin_amdgcn_global_load_lds(
        (const __attribute__((address_space(1))) unsigned int*)g,
        (__attribute__((address_space(3))) unsigned int*)l, 16, 0, 0);
}

// ---------------------------------------------------------------------------
// Swizzled workspace layouts (so linear global_load_lds staging lands data
// pre-swizzled in LDS; 16B chunk = 8 bf16):
//  K buffer ("Ks"): per (sk_blk = sk/64, c = d/128) region of 1024 chunks:
//     chunk L holds key[sk_blk*64 + L/16][c*128 + ((L&15)^((L/16)&15))*8 ..+8]
//  V^T buffer ("Vs"): per (sk_blk = sk/64) region of 2048 chunks:
//     chunk L holds vt[L/8][sk_blk*64 + ((L&7)^((L/8)&7))*8 ..+8]
// ---------------------------------------------------------------------------

// Generic NT GEMM: C[m][n] = sum_k A[m][k]*B[n][k], A:MxK f32, B:NxK f32.
// Epilogue writes bf16 into swizzled layout per `mode` (0 = Ks, 1 = Vs).
// Tiles 64x64, block=256 (4 waves x 16 rows), Kc=128. grid = (M/64, N/64)
__global__ __launch_bounds__(256, 2) void gemm_nt_f32_bf16_swz(
    const float* __restrict__ A, const float* __restrict__ Bm,
    unsigned short* __restrict__ C, int M, int N, int K, int mode)
{
    __shared__ short sA[64*128];   // 16 KB
    __shared__ short sB[64*128];   // 16 KB
    const int tid  = threadIdx.x;
    const int wave = tid >> 6;
    const int lane = tid & 63;
    const int quad = lane >> 4;
    const int l15  = lane & 15;
    const int m0 = blockIdx.x * 64;
    const int n0 = blockIdx.y * 64;

    f32x4 acc[4];
    #pragma unroll
    for (int n = 0; n < 4; ++n) { acc[n][0]=0.f; acc[n][1]=0.f; acc[n][2]=0.f; acc[n][3]=0.f; }

    for (int kc = 0; kc < K; kc += 128) {
        __syncthreads();
        #pragma unroll
        for (int it = 0; it < 8; ++it) {
            int f = it*1024 + tid*4;          // element index in 64x128 tile
            int row = f >> 7, col = f & 127;
            float4 av = *(const float4*)(A + (size_t)(m0+row)*K + kc + col);
            bf16x4 a4; a4[0]=f2bf(av.x); a4[1]=f2bf(av.y); a4[2]=f2bf(av.z); a4[3]=f2bf(av.w);
            *(bf16x4*)(sA + f) = a4;
            float4 bv = *(const float4*)(Bm + (size_t)(n0+row)*K + kc + col);
            bf16x4 b4; b4[0]=f2bf(bv.x); b4[1]=f2bf(bv.y); b4[2]=f2bf(bv.z); b4[3]=f2bf(bv.w);
            *(bf16x4*)(sB + f) = b4;
        }
        __syncthreads();
        #pragma unroll
        for (int t = 0; t < 4; ++t) {
            bf16x8 af = *(const bf16x8*)(sA + (wave*16 + l15)*128 + t*32 + quad*8);
            #pragma unroll
            for (int n = 0; n < 4; ++n) {
                bf16x8 bfr = *(const bf16x8*)(sB + (n*16 + l15)*128 + t*32 + quad*8);
                acc[n] = __builtin_amdgcn_mfma_f32_16x16x32_bf16(af, bfr, acc[n], 0, 0, 0);
            }
        }
    }
    // epilogue: D row=quad*4+r, col=l15; scatter 2B stores into swizzled layout
    #pragma unroll
    for (int n = 0; n < 4; ++n)
        #pragma unroll
        for (int r = 0; r < 4; ++r) {
            int m  = m0 + wave*16 + quad*4 + r;
            int nn = n0 + n*16 + l15;
            size_t idx;
            if (mode == 0) {  // Ks: key[m=sk][nn=d]
                idx = ((size_t)(m>>6)*4 + (nn>>7))*8192
                    + (size_t)((m&63)*16 + (((nn>>3)&15) ^ (m&15)))*8 + (nn&7);
            } else {          // Vs: vt[m=dv][nn=sk]
                idx = (size_t)(nn>>6)*16384
                    + (size_t)(m*8 + (((nn>>3)&7) ^ (m&7)))*8 + (nn&7);
            }
            C[idx] = (unsigned short)f2bf(acc[n][r]);
        }
}

// ---------------------------------------------------------------------------
// Fused attention (one SK split half per block):
//  grid = (NROWS/64, SPLIT), block = 256 (4 waves x 16 Q-rows).
//  Q (x scale) in registers; K staged 64x128 chunks (swizzled), V^T staged
//  256x64 (swizzled); online softmax in C-layout; P->LDS (swizzled)->A-frag.
//  Writes unnormalized O, m, l per split; combine kernel merges.
// ---------------------------------------------------------------------------
__global__ __launch_bounds__(256, 2) void attn_fused(
    const float* __restrict__ X,            // [16384][512] fp32
    const unsigned short* __restrict__ Kb,  // key bf16, Ks swizzled layout
    const unsigned short* __restrict__ Vt,  // V^T bf16, Vs swizzled layout
    float* __restrict__ Opart,              // [SPLIT][16384][256]
    float* __restrict__ Mpart,              // [SPLIT][16384]
    float* __restrict__ Lpart)              // [SPLIT][16384]
{
    __shared__ short sK[64*128];    // 16 KB
    __shared__ short sV[256*64];    // 32 KB
    __shared__ short sP[4*16*64];   // 8 KB (wave-private quarters)
    const int tid  = threadIdx.x;
    const int wave = tid >> 6;
    const int lane = tid & 63;
    const int quad = lane >> 4;
    const int l15  = lane & 15;
    const int l7   = lane & 7;
    const int q0   = blockIdx.x * 64;
    const int split = blockIdx.y;
    const float scale = 0.04419417382415922f;  // 1/sqrt(512)

    // Q fragments (scale folded): A[m=l15][k=quad*8+j], 16 k-steps
    bf16x8 qf[16];
    {
        const float* xrow = X + (size_t)(q0 + wave*16 + l15) * DDIM;
        #pragma unroll
        for (int t = 0; t < 16; ++t) {
            float4 a = *(const float4*)(xrow + t*32 + quad*8);
            float4 b = *(const float4*)(xrow + t*32 + quad*8 + 4);
            bf16x8 q;
            q[0]=f2bf(a.x*scale); q[1]=f2bf(a.y*scale); q[2]=f2bf(a.z*scale); q[3]=f2bf(a.w*scale);
            q[4]=f2bf(b.x*scale); q[5]=f2bf(b.y*scale); q[6]=f2bf(b.z*scale); q[7]=f2bf(b.w*scale);
            qf[t] = q;
        }
    }

    f32x4 o[16];
    #pragma unroll
    for (int i = 0; i < 16; ++i) { o[i][0]=0.f; o[i][1]=0.f; o[i][2]=0.f; o[i][3]=0.f; }
    float m_r[4] = {-1e30f,-1e30f,-1e30f,-1e30f};
    float l_r[4] = {0.f,0.f,0.f,0.f};
    short* sPw = sP + wave*(16*64);

    for (int j = 0; j < SKH/64; ++j) {
        const int sk0 = split*SKH + j*64;
        const int sk_blk = sk0 >> 6;
        f32x4 s[4];
        #pragma unroll
        for (int n = 0; n < 4; ++n) { s[n][0]=0.f; s[n][1]=0.f; s[n][2]=0.f; s[n][3]=0.f; }

        #pragma unroll
        for (int c = 0; c < 4; ++c) {
            __syncthreads();
            if (c == 0) {
                // stage V^T region (32 KB): pure linear copy (pre-swizzled)
                const unsigned short* vbase = Vt + (size_t)sk_blk*16384;
                #pragma unroll
                for (int it = 0; it < 8; ++it)
                    gload_lds16(vbase + it*2048 + tid*8,
                                (char*)sV + it*4096 + wave*1024);
            }
            // stage K region (16 KB): pure linear copy (pre-swizzled)
            const unsigned short* kbase = Kb + ((size_t)sk_blk*4 + c)*8192;
            #pragma unroll
            for (int it = 0; it < 4; ++it)
                gload_lds16(kbase + it*2048 + tid*8,
                            (char*)sK + it*4096 + wave*1024);
            __syncthreads();
            // S += Q_chunk * K_chunk^T   (swizzled B-frag reads, conflict-free)
            #pragma unroll
            for (int t = 0; t < 4; ++t) {
                bf16x8 af = qf[c*4 + t];
                #pragma unroll
                for (int n = 0; n < 4; ++n) {
                    bf16x8 bfr = *(const bf16x8*)(sK + (n*16 + l15)*128
                                                  + (((t*4 + quad) ^ l15) << 3));
                    s[n] = __builtin_amdgcn_mfma_f32_16x16x32_bf16(af, bfr, s[n], 0, 0, 0);
                }
            }
        }

        // ---- online softmax (rows = quad*4+r) ----
        float alpha[4];
        float p[4][4];
        #pragma unroll
        for (int r = 0; r < 4; ++r) {
            float v = fmaxf(fmaxf(s[0][r], s[1][r]), fmaxf(s[2][r], s[3][r]));
            v = fmaxf(v, __shfl_xor(v, 1));
            v = fmaxf(v, __shfl_xor(v, 2));
            v = fmaxf(v, __shfl_xor(v, 4));
            v = fmaxf(v, __shfl_xor(v, 8));
            float mn = fmaxf(m_r[r], v);
            alpha[r] = __expf(m_r[r] - mn);
            m_r[r] = mn;
            float sum = 0.f;
            #pragma unroll
            for (int n = 0; n < 4; ++n) {
                float pv = __expf(s[n][r] - mn);
                p[n][r] = pv;
                sum += pv;
            }
            sum += __shfl_xor(sum, 1);
            sum += __shfl_xor(sum, 2);
            sum += __shfl_xor(sum, 4);
            sum += __shfl_xor(sum, 8);
            l_r[r] = l_r[r]*alpha[r] + sum;
        }
        #pragma unroll
        for (int n2 = 0; n2 < 16; ++n2)
            #pragma unroll
            for (int r = 0; r < 4; ++r) o[n2][r] *= alpha[r];
        // P -> wave-private LDS, swizzled (chunk ^= row&7); same-wave read below
        #pragma unroll
        for (int n = 0; n < 4; ++n)
            #pragma unroll
            for (int r = 0; r < 4; ++r) {
                int row = quad*4 + r;
                int cch = n*2 + (l15 >> 3);
                sPw[row*64 + (((cch ^ (row & 7)) << 3)) + l7] = f2bf(p[n][r]);
            }
        // ---- O += P * V^T (swizzled A and B frag reads, conflict-free) ----
        #pragma unroll
        for (int t2 = 0; t2 < 2; ++t2) {
            bf16x8 af = *(const bf16x8*)(sPw + l15*64
                                         + (((t2*4 + quad) ^ l7) << 3));
            #pragma unroll
            for (int n2 = 0; n2 < 16; ++n2) {
                bf16x8 bfr = *(const bf16x8*)(sV + (n2*16 + l15)*64
                                              + (((t2*4 + quad) ^ l7) << 3));
                o[n2] = __builtin_amdgcn_mfma_f32_16x16x32_bf16(af, bfr, o[n2], 0, 0, 0);
            }
        }
    }

    // epilogue: unnormalized O + (m,l) per row
    const size_t base = (size_t)split * NROWS;
    #pragma unroll
    for (int r = 0; r < 4; ++r) {
        int row = q0 + wave*16 + quad*4 + r;
        if (l15 == 0) { Mpart[base + row] = m_r[r]; Lpart[base + row] = l_r[r]; }
        float* orow = Opart + (base + row) * (size_t)DVDIM;
        #pragma unroll
        for (int n2 = 0; n2 < 16; ++n2)
            orow[n2*16 + l15] = o[n2][r];
    }
}

// ---------------------------------------------------------------------------
// Combine the two SK-split partials: out = (O0*w0 + O1*w1)/(l0*w0 + l1*w1)
// grid = NROWS, block = 256 (= DV)
// ---------------------------------------------------------------------------
__global__ void combine_splits(
    const float* __restrict__ Opart, const float* __restrict__ Mpart,
    const float* __restrict__ Lpart, float* __restrict__ out)
{
    const int row = blockIdx.x;
    const int dv  = threadIdx.x;
    const size_t idx = (size_t)row * DVDIM + dv;
    float m0 = Mpart[row],         m1 = Mpart[NROWS + row];
    float l0 = Lpart[row],         l1 = Lpart[NROWS + row];
    float M  = fmaxf(m0, m1);
    float w0 = __expf(m0 - M), w1 = __expf(m1 - M);
    float denom = l0*w0 + l1*w1;
    float o0 = Opart[idx];
    float o1 = Opart[(size_t)NROWS*DVDIM + idx];
    out[idx] = (o0*w0 + o1*w1) / denom;
}

extern "C" void kernel_launch(void* const* d_in, const int* in_sizes, int n_in,
                              void* d_out, int out_size, void* d_ws, size_t ws_size,
                              hipStream_t stream) {
    const float* X  = (const float*)d_in[0];   // [8,2048,512]
    const float* Y  = (const float*)d_in[1];   // [4096,512]
    const float* Z  = (const float*)d_in[2];   // [4096,512]
    const float* Wk = (const float*)d_in[3];   // [512,512]
    const float* Wv = (const float*)d_in[4];   // [256,512]
    float* out = (float*)d_out;

    // workspace layout (~40.3 MB total)
    char* ws = (char*)d_ws;
    unsigned short* keyb = (unsigned short*)(ws);                  // 4 MB: Ks swizzled
    unsigned short* vtb  = (unsigned short*)(ws + (4u<<20));       // 2 MB: Vs swizzled
    float* Opart = (float*)(ws + (8u<<20));                        // 32 MB
    float* Mpart = (float*)(ws + (8u<<20) + 33554432u);            // 128 KB
    float* Lpart = (float*)(ws + (8u<<20) + 33554432u + 131072u);  // 128 KB

    // key[s][d] = sum_c Y[s][c] * Wk[d][c]  -> Ks swizzled
    gemm_nt_f32_bf16_swz<<<dim3(SKN/64, DDIM/64), dim3(256), 0, stream>>>(
        Y, Wk, keyb, SKN, DDIM, DDIM, 0);
    // vt[d][s] = sum_c Wv[d][c] * Z[s][c]   -> Vs swizzled
    gemm_nt_f32_bf16_swz<<<dim3(DVDIM/64, SKN/64), dim3(256), 0, stream>>>(
        Wv, Z, vtb, DVDIM, SKN, DDIM, 1);
    // fused attention over SK split halves
    attn_fused<<<dim3(NROWS/64, SPLIT), dim3(256), 0, stream>>>(
        X, keyb, vtb, Opart, Mpart, Lpart);
    // merge splits
    combine_splits<<<dim3(NROWS), dim3(256), 0, stream>>>(Opart, Mpart, Lpart, out);
}